// Round 1
// baseline (155.997 us; speedup 1.0000x reference)
//
#include <hip/hip_runtime.h>
#include <math.h>

#define PI_D 3.14159265358979323846

// Month-boundary tables (match numpy NDAYS/CDAYS)
__constant__ int   c_CDAYS[13] = {0,31,59,90,120,151,181,212,243,273,304,334,365};
__constant__ double c_NDAYS[13] = {0,31,28,31,30,31,30,31,31,30,31,30,31};

// ---------------- Kernel A: insolation factors L[12], gE[12] ----------------
// One block. Double precision to match the numpy float64 host computation,
// cast to float at the end (reference casts to float32).
__global__ void k_insol(const int* __restrict__ phi_ptr, float* __restrict__ LgE) {
    __shared__ double dtsi_s[365];
    __shared__ double maxd_s;
    const int t = threadIdx.x;
    const double latr = (double)(*phi_ptr) * PI_D / 180.0;
    if (t < 365) {
        double jday = (double)(t + 1);
        double sd = asin(sin(PI_D * 23.5 / 180.0) * sin(PI_D * (jday - 80.0) / 180.0));
        double y = -tan(latr) * tan(sd);
        y = fmin(1.0, fmax(-1.0, y));
        double hdl = acos(y);
        dtsi_s[t] = hdl * sin(latr) * sin(sd) + cos(latr) * cos(sd) * sin(hdl);
    }
    __syncthreads();
    if (t == 0) {
        double mx = dtsi_s[0];
        for (int i = 1; i < 365; ++i) mx = fmax(mx, dtsi_s[i]);
        maxd_s = mx;
    }
    __syncthreads();
    if (t < 12) {
        const int c0 = c_CDAYS[t], c1 = c_CDAYS[t + 1];
        double s = 0.0;
        for (int i = c0; i < c1; ++i) s += dtsi_s[i];
        double gE = (s / (double)(c1 - c0)) / maxd_s;
        // day-length factor L
        double jm = (double)c0 + 0.5 * c_NDAYS[t + 1];
        double ms = 1.0 - tan(latr) * tan(23.439 * PI_D / 180.0 * cos(jm * PI_D / 182.625));
        ms = fmin(2.0, fmax(0.0, ms));
        double nhrs = 24.0 * acos(1.0 - ms) / PI_D;
        double L = c_NDAYS[t + 1] / 30.0 * (nhrs / 12.0);
        LgE[t] = (float)L;
        LgE[12 + t] = (float)gE;
    }
}

// ---------------- Kernel B: Thornthwaite PET, one thread per year ----------------
__global__ void k_pet(const float* __restrict__ T, const float* __restrict__ LgE,
                      float* __restrict__ Ep, int nyrs) {
    int y = blockIdx.x * blockDim.x + threadIdx.x;
    if (y >= nyrs) return;
    float Tv[12];
#pragma unroll
    for (int m = 0; m < 12; ++m) Tv[m] = T[y * 12 + m];
    float I = 0.f;
#pragma unroll
    for (int m = 0; m < 12; ++m) {
        float is = fmaxf(Tv[m] * 0.2f, 0.f);   // T/5
        I += powf(is, 1.514f);
    }
    float a = 6.75e-07f * I * I * I - 7.71e-05f * I * I + 0.0179f * I + 0.49f;
#pragma unroll
    for (int m = 0; m < 12; ++m) {
        float t = Tv[m];
        float ep;
        if (t < 0.f) {
            ep = 0.f;
        } else if (t < 26.5f) {
            float ts = fminf(fmaxf(t, 0.f), 26.5f);
            ep = 16.f * LgE[m] * powf(10.f * ts / I, a);
        } else {
            ep = -415.85f + 32.25f * t - 0.43f * t * t;
        }
        Ep[y * 12 + m] = ep;
    }
}

// ---------------- Kernel C: contractive-scan soil moisture + width ----------------
// One thread per year. Warm-up WARM months starting from a guess (M0); the
// recurrence is contractive (|dnewM/dprevM| <= 1-ALPH = 0.907), so after 144
// steps the initial-condition error is <= 0.56*0.907^144 ~ 4e-7 — below
// float32 state noise. Thread for year 0 (and any w0==0) starts exactly at M0.
#define WARM 144
#define M0f   0.2f
#define MMAXf 0.76f
#define MMINf 0.01f

__global__ void k_scan(const float* __restrict__ T, const float* __restrict__ P,
                       const float* __restrict__ Ep, const float* __restrict__ LgE,
                       const float* __restrict__ T1p, const float* __restrict__ T2p,
                       const float* __restrict__ M1p, const float* __restrict__ M2p,
                       float* __restrict__ width, int nyrs) {
    int y = blockIdx.x * blockDim.x + threadIdx.x;
    if (y >= nyrs) return;
    const float T1 = *T1p, T2 = *T2p, M1 = *M1p, M2 = *M2p;
    const float cG = (float)(5.8 * 0.093 / 6.8);   // MU_TH*ALPH/(1+MU_TH)
    const float cR = (float)(0.093 / 6.8);         // ALPH/(1+MU_TH)

    const int s = y * 12;
    int w0 = s - WARM; if (w0 < 0) w0 = 0;
    float M = M0f;   // exact when w0==0, converged guess otherwise

    for (int t = w0; t < s; ++t) {
        float p = P[t], ep = Ep[t];
        float frac = M * (1.0f / MMAXf);
        float Et = ep * frac;
        float R  = p * powf(frac, 4.886f) + cR * M * 1000.f;
        float G  = cG * M * 1000.f;
        float dW = p - Et - R - G;
        M = M + dW * (1.0f / 1000.0f);
        M = fminf(MMAXf, fmaxf(MMINf, M));
    }

    float acc = 0.f;
#pragma unroll
    for (int m = 0; m < 12; ++m) {
        int t = s + m;
        float p = P[t], ep = Ep[t];
        float frac = M * (1.0f / MMAXf);
        float Et = ep * frac;
        float R  = p * powf(frac, 4.886f) + cR * M * 1000.f;
        float G  = cG * M * 1000.f;
        float dW = p - Et - R - G;
        M = M + dW * (1.0f / 1000.0f);
        M = fminf(MMAXf, fmaxf(MMINf, M));

        float gT = fminf(fmaxf((T[t] - T1) / (T2 - T1), 0.f), 1.f);
        float gM = fminf(fmaxf((M - M1) / (M2 - M1), 0.f), 1.f);
        acc += fminf(gT, gM) * LgE[12 + m];
    }
    width[y] = acc;
}

// ---------------- Kernel D: z-score normalize (single block) ----------------
__global__ void k_norm(const float* __restrict__ width, float* __restrict__ out, int n) {
    __shared__ double s_sum[256];
    __shared__ double s_sq[256];
    __shared__ float mean_s, inv_s;
    const int t = threadIdx.x;
    double sm = 0.0, sq = 0.0;
    for (int i = t; i < n; i += 256) {
        double w = (double)width[i];
        sm += w; sq += w * w;
    }
    s_sum[t] = sm; s_sq[t] = sq;
    __syncthreads();
    for (int off = 128; off > 0; off >>= 1) {
        if (t < off) { s_sum[t] += s_sum[t + off]; s_sq[t] += s_sq[t + off]; }
        __syncthreads();
    }
    if (t == 0) {
        double mean = s_sum[0] / (double)n;
        double var = (s_sq[0] - (double)n * mean * mean) / (double)(n - 1);
        mean_s = (float)mean;
        inv_s = (float)(1.0 / sqrt(var));
    }
    __syncthreads();
    for (int i = t; i < n; i += 256) {
        out[i] = (width[i] - mean_s) * inv_s;
    }
}

extern "C" void kernel_launch(void* const* d_in, const int* in_sizes, int n_in,
                              void* d_out, int out_size, void* d_ws, size_t ws_size,
                              hipStream_t stream) {
    // inputs: 0=syear(int) 1=eyear(int) 2=phi(int) 3=T(f32) 4=P(f32)
    //         5=T1 6=T2 7=M1 8=M2 (f32 scalars)
    const int*   phi = (const int*)d_in[2];
    const float* T   = (const float*)d_in[3];
    const float* P   = (const float*)d_in[4];
    const float* T1  = (const float*)d_in[5];
    const float* T2  = (const float*)d_in[6];
    const float* M1  = (const float*)d_in[7];
    const float* M2  = (const float*)d_in[8];
    float* out = (float*)d_out;

    const int nyrs = in_sizes[3] / 12;       // 8192
    const int nmon = nyrs * 12;              // 98304

    float* ws    = (float*)d_ws;
    float* LgE   = ws;                       // 24 floats (pad to 32)
    float* Ep    = ws + 32;                  // nmon floats
    float* width = ws + 32 + nmon;           // nyrs floats

    k_insol<<<1, 384, 0, stream>>>(phi, LgE);
    k_pet<<<(nyrs + 255) / 256, 256, 0, stream>>>(T, LgE, Ep, nyrs);
    k_scan<<<(nyrs + 255) / 256, 256, 0, stream>>>(T, P, Ep, LgE, T1, T2, M1, M2, width, nyrs);
    k_norm<<<1, 256, 0, stream>>>(width, out, nyrs);
}

// Round 2
// 100.725 us; speedup vs baseline: 1.5487x; 1.5487x over previous
//
#include <hip/hip_runtime.h>
#include <math.h>

#define PI_D 3.14159265358979323846
#define WARM_Y 12          // warm-up years: 0.907^144 * 0.56 ~ 4e-7 residual in M
#define BY 256             // years per scan block
#define NGRP (BY + WARM_Y) // 268 year-groups staged per block
#define NPAD (NGRP * 13)   // padded LDS floats per array (stride 13 = conflict-free)

// Fast hardware log2/exp2 (v_log_f32 / v_exp_f32). Inputs always >= 0 here;
// x==0 -> log2=-inf -> exp2(-inf)=0, matching pow(0,y)=0.
#if __has_builtin(__builtin_amdgcn_logf) && __has_builtin(__builtin_amdgcn_exp2f)
__device__ __forceinline__ float flog2(float x) { return __builtin_amdgcn_logf(x); }
__device__ __forceinline__ float fexp2(float x) { return __builtin_amdgcn_exp2f(x); }
#else
__device__ __forceinline__ float flog2(float x) { return log2f(x); }
__device__ __forceinline__ float fexp2(float x) { return exp2f(x); }
#endif
__device__ __forceinline__ float fpow(float x, float y) { return fexp2(y * flog2(x)); }

__constant__ int    c_CDAYS[13] = {0,31,59,90,120,151,181,212,243,273,304,334,365};
__constant__ double c_NDAYS[13] = {0,31,28,31,30,31,30,31,31,30,31,30,31};

// ---------------- Kernel A: insolation factors L[12], gE[12] (float64 math) ---------
__global__ void k_insol(const int* __restrict__ phi_ptr, float* __restrict__ LgE) {
    __shared__ double dtsi_s[365];
    __shared__ double red[64];
    __shared__ double maxd_s;
    const int t = threadIdx.x;
    const double latr = (double)(*phi_ptr) * PI_D / 180.0;
    if (t < 365) {
        double jday = (double)(t + 1);
        double sd = asin(sin(PI_D * 23.5 / 180.0) * sin(PI_D * (jday - 80.0) / 180.0));
        double y = -tan(latr) * tan(sd);
        y = fmin(1.0, fmax(-1.0, y));
        double hdl = acos(y);
        dtsi_s[t] = hdl * sin(latr) * sin(sd) + cos(latr) * cos(sd) * sin(hdl);
    }
    __syncthreads();
    if (t < 64) {
        double mx = -1e300;
        for (int i = t; i < 365; i += 64) mx = fmax(mx, dtsi_s[i]);
        red[t] = mx;
    }
    __syncthreads();
    if (t == 0) {
        double mx = red[0];
        for (int i = 1; i < 64; ++i) mx = fmax(mx, red[i]);
        maxd_s = mx;
    }
    __syncthreads();
    if (t < 12) {
        const int c0 = c_CDAYS[t], c1 = c_CDAYS[t + 1];
        double s = 0.0;
        for (int i = c0; i < c1; ++i) s += dtsi_s[i];
        double gE = (s / (double)(c1 - c0)) / maxd_s;
        double jm = (double)c0 + 0.5 * c_NDAYS[t + 1];
        double ms = 1.0 - tan(latr) * tan(23.439 * PI_D / 180.0 * cos(jm * PI_D / 182.625));
        ms = fmin(2.0, fmax(0.0, ms));
        double nhrs = 24.0 * acos(1.0 - ms) / PI_D;
        double L = c_NDAYS[t + 1] / 30.0 * (nhrs / 12.0);
        LgE[t] = (float)L;
        LgE[12 + t] = (float)gE;
    }
}

// ---------------- Kernel B: Thornthwaite PET -> linear coefficient A[t] -------------
// A[t] = 1 - ALPH - Ep[t]/(MMAX*ROOTD); the soil step becomes M' = A*M + B*(1-pw).
__global__ void k_pet(const float* __restrict__ T, const float* __restrict__ LgE,
                      float* __restrict__ A, int nyrs) {
    int y = blockIdx.x * blockDim.x + threadIdx.x;
    if (y >= nyrs) return;
    float Tv[12];
    {
        const float4* T4 = (const float4*)(T + y * 12);
        float4 a = T4[0], b = T4[1], c = T4[2];
        Tv[0]=a.x; Tv[1]=a.y; Tv[2]=a.z; Tv[3]=a.w;
        Tv[4]=b.x; Tv[5]=b.y; Tv[6]=b.z; Tv[7]=b.w;
        Tv[8]=c.x; Tv[9]=c.y; Tv[10]=c.z; Tv[11]=c.w;
    }
    float I = 0.f;
#pragma unroll
    for (int m = 0; m < 12; ++m) {
        float is = fmaxf(Tv[m] * 0.2f, 0.f);
        I += fpow(is, 1.514f);
    }
    float a = 6.75e-07f * I * I * I - 7.71e-05f * I * I + 0.0179f * I + 0.49f;
    float rI = 10.0f / I;
    float Av[12];
#pragma unroll
    for (int m = 0; m < 12; ++m) {
        float t = Tv[m];
        float ep;
        if (t < 0.f) {
            ep = 0.f;
        } else if (t < 26.5f) {
            ep = 16.f * LgE[m] * fpow(t * rI, a);
        } else {
            ep = -415.85f + 32.25f * t - 0.43f * t * t;
        }
        Av[m] = (1.0f - 0.093f) - ep * (1.0f / 760.0f);
    }
    float4* A4 = (float4*)(A + y * 12);
    A4[0] = make_float4(Av[0], Av[1], Av[2], Av[3]);
    A4[1] = make_float4(Av[4], Av[5], Av[6], Av[7]);
    A4[2] = make_float4(Av[8], Av[9], Av[10], Av[11]);
}

// ---------------- Kernel C: contractive soil-moisture scan + width ------------------
// One thread per year; 12 warm-up years from M0 guess (contraction |J|<=0.907 =>
// residual ~4e-7). A/P/T staged in LDS, padded layout g*13+m (13 coprime 32 banks).
__global__ void k_scan(const float* __restrict__ T, const float* __restrict__ P,
                       const float* __restrict__ A, const float* __restrict__ LgE,
                       const float* __restrict__ T1p, const float* __restrict__ T2p,
                       const float* __restrict__ M1p, const float* __restrict__ M2p,
                       float* __restrict__ width, int nyrs) {
    __shared__ float sA[NPAD];
    __shared__ float sB[NPAD];
    __shared__ float sT[NPAD];
    __shared__ float sGE[12];
    const int nmon = nyrs * 12;
    const int base = (blockIdx.x * BY - WARM_Y) * 12;   // global month of staged idx 0

    for (int t = threadIdx.x; t < NGRP * 12; t += BY) {
        int tg = base + t;
        int pt = t + t / 12;                            // g*13 + m
        float a = 1.0f, p = 0.0f, tt = 0.0f;
        if (tg >= 0 && tg < nmon) { a = A[tg]; p = P[tg]; tt = T[tg]; }
        sA[pt] = a;
        sB[pt] = p * 1e-3f;
        sT[pt] = tt;
    }
    if (threadIdx.x < 12) sGE[threadIdx.x] = LgE[12 + threadIdx.x];
    __syncthreads();

    const int ly = threadIdx.x;
    const int y = blockIdx.x * BY + ly;
    if (y >= nyrs) return;

    const float T1 = *T1p, T2 = *T2p, M1 = *M1p, M2 = *M2p;
    const float invT = 1.0f / (T2 - T1);
    const float invM = 1.0f / (M2 - M1);

    float M = 0.2f;
    // first years of the sequence start exactly at t=0 (fewer warm groups, exact M0)
    int g0 = (blockIdx.x == 0) ? (ly < WARM_Y ? WARM_Y : ly) : ly;

    for (int g = g0; g < ly + WARM_Y; ++g) {
        int pt = g * 13;
#pragma unroll
        for (int m = 0; m < 12; ++m) {
            float a = sA[pt + m], b = sB[pt + m];
            float frac = M * (1.0f / 0.76f);
            float pw = fexp2(4.886f * flog2(frac));
            float K = fmaf(a, M, b);
            M = fmaf(-b, pw, K);
            M = fminf(0.76f, fmaxf(0.01f, M));
        }
    }
    {
        int pt = (ly + WARM_Y) * 13;
        float acc = 0.f;
#pragma unroll
        for (int m = 0; m < 12; ++m) {
            float a = sA[pt + m], b = sB[pt + m];
            float frac = M * (1.0f / 0.76f);
            float pw = fexp2(4.886f * flog2(frac));
            float K = fmaf(a, M, b);
            M = fmaf(-b, pw, K);
            M = fminf(0.76f, fmaxf(0.01f, M));
            float gT = fminf(fmaxf((sT[pt + m] - T1) * invT, 0.f), 1.f);
            float gM = fminf(fmaxf((M - M1) * invM, 0.f), 1.f);
            acc += fminf(gT, gM) * sGE[m];
        }
        width[y] = acc;
    }
}

// ---------------- Kernel D: z-score normalize (single block) ------------------------
__global__ void k_norm(const float* __restrict__ width, float* __restrict__ out, int n) {
    __shared__ double s_sum[256];
    __shared__ double s_sq[256];
    __shared__ float mean_s, inv_s;
    const int t = threadIdx.x;
    double sm = 0.0, sq = 0.0;
    for (int i = t; i < n; i += 256) {
        double w = (double)width[i];
        sm += w; sq += w * w;
    }
    s_sum[t] = sm; s_sq[t] = sq;
    __syncthreads();
    for (int off = 128; off > 0; off >>= 1) {
        if (t < off) { s_sum[t] += s_sum[t + off]; s_sq[t] += s_sq[t + off]; }
        __syncthreads();
    }
    if (t == 0) {
        double mean = s_sum[0] / (double)n;
        double var = (s_sq[0] - (double)n * mean * mean) / (double)(n - 1);
        mean_s = (float)mean;
        inv_s = (float)(1.0 / sqrt(var));
    }
    __syncthreads();
    for (int i = t; i < n; i += 256) {
        out[i] = (width[i] - mean_s) * inv_s;
    }
}

extern "C" void kernel_launch(void* const* d_in, const int* in_sizes, int n_in,
                              void* d_out, int out_size, void* d_ws, size_t ws_size,
                              hipStream_t stream) {
    // inputs: 0=syear 1=eyear 2=phi(int) 3=T(f32) 4=P(f32) 5=T1 6=T2 7=M1 8=M2
    const int*   phi = (const int*)d_in[2];
    const float* T   = (const float*)d_in[3];
    const float* P   = (const float*)d_in[4];
    const float* T1  = (const float*)d_in[5];
    const float* T2  = (const float*)d_in[6];
    const float* M1  = (const float*)d_in[7];
    const float* M2  = (const float*)d_in[8];
    float* out = (float*)d_out;

    const int nyrs = in_sizes[3] / 12;   // 8192
    const int nmon = nyrs * 12;

    float* ws    = (float*)d_ws;
    float* LgE   = ws;                   // 32 floats
    float* A     = ws + 32;              // nmon floats
    float* width = ws + 32 + nmon;       // nyrs floats

    k_insol<<<1, 384, 0, stream>>>(phi, LgE);
    k_pet<<<(nyrs + 255) / 256, 256, 0, stream>>>(T, LgE, A, nyrs);
    k_scan<<<(nyrs + BY - 1) / BY, BY, 0, stream>>>(T, P, A, LgE, T1, T2, M1, M2, width, nyrs);
    k_norm<<<1, 256, 0, stream>>>(width, out, nyrs);
}

// Round 3
// 98.184 us; speedup vs baseline: 1.5888x; 1.0259x over previous
//
#include <hip/hip_runtime.h>
#include <math.h>

#define PI_F 3.14159265358979323846f
#define WARM_Y 12          // warm-up years: 0.907^144 * 0.56 ~ 4e-7 residual in M
#define BY 64              // years per block
#define BS 64              // threads per block (1 wave)
#define NGRP (BY + WARM_Y) // 76 year-groups staged per block
#define NPAD (NGRP * 13)   // padded LDS floats (stride 13 -> conflict-free)

// Hardware log2/exp2 (v_log_f32/v_exp_f32). Args >= 0 here; 0 -> -inf -> 0 = pow(0,y).
#if __has_builtin(__builtin_amdgcn_logf) && __has_builtin(__builtin_amdgcn_exp2f)
__device__ __forceinline__ float flog2(float x) { return __builtin_amdgcn_logf(x); }
__device__ __forceinline__ float fexp2(float x) { return __builtin_amdgcn_exp2f(x); }
#else
__device__ __forceinline__ float flog2(float x) { return log2f(x); }
__device__ __forceinline__ float fexp2(float x) { return exp2f(x); }
#endif
__device__ __forceinline__ float fpow(float x, float y) { return fexp2(y * flog2(x)); }

__constant__ int   c_CDAYS[13]  = {0,31,59,90,120,151,181,212,243,273,304,334,365};
__constant__ float c_NDAYSF[13] = {0,31,28,31,30,31,30,31,31,30,31,30,31};

// 4.886 * log2(1/0.76)  (folds frac=M/0.76 into the exponent)
#define POW_C 1.9345076f

// ---------------- Fused kernel: insolation + PET + contractive scan ----------------
// One wave per block, one thread per year. Each block independently:
//  1. computes day-length L[12] and insolation gE[12] (f32 trig, identical per block)
//  2. stages its T/P month range into padded LDS
//  3. computes PET -> linear step coefficient A per staged month
//  4. runs the 12-year warm-up + 1 real year soil-moisture chain per thread
// Widths land directly in d_out; k_norm below z-scores in place.
__global__ void k_fused(const int* __restrict__ phi_ptr,
                        const float* __restrict__ T, const float* __restrict__ P,
                        const float* __restrict__ T1p, const float* __restrict__ T2p,
                        const float* __restrict__ M1p, const float* __restrict__ M2p,
                        float* __restrict__ width, int nyrs) {
    __shared__ float sA[NPAD];
    __shared__ float sB[NPAD];
    __shared__ float sT[NPAD];
    __shared__ float dtsi[365];
    __shared__ float sL[12], sGE[12];
    __shared__ float maxd;

    const int tid = threadIdx.x;
    const float latr = (float)(*phi_ptr) * (PI_F / 180.f);
    const float tl = tanf(latr), slat = sinf(latr), clat = cosf(latr);
    const float T1 = *T1p, T2 = *T2p, M1 = *M1p, M2 = *M2p;

    // ---- insolation daily curve ----
    for (int d = tid; d < 365; d += BS) {
        float jd = (float)(d + 1);
        float sd = asinf(sinf(PI_F * 23.5f / 180.f) * sinf(PI_F * (jd - 80.f) / 180.f));
        float y  = fminf(1.f, fmaxf(-1.f, -tl * tanf(sd)));
        float hdl = acosf(y);
        dtsi[d] = hdl * slat * sinf(sd) + clat * cosf(sd) * sinf(hdl);
    }

    // ---- stage T, P (B = P/1000) ----
    const int nmon = nyrs * 12;
    const int base = (blockIdx.x * BY - WARM_Y) * 12;
    for (int t = tid; t < NGRP * 12; t += BS) {
        int tg = base + t;
        int pt = t + t / 12;                 // g*13 + m
        float p = 0.f, tt = 0.f;
        if (tg >= 0 && tg < nmon) { p = P[tg]; tt = T[tg]; }
        sB[pt] = p * 1e-3f;
        sT[pt] = tt;
    }
    __syncthreads();

    // ---- max(dtsi) wave reduction ----
    {
        float mx = -1e30f;
        for (int i = tid; i < 365; i += BS) mx = fmaxf(mx, dtsi[i]);
        for (int off = 32; off > 0; off >>= 1) mx = fmaxf(mx, __shfl_down(mx, off));
        if (tid == 0) maxd = mx;
    }
    __syncthreads();

    // ---- monthly L, gE ----
    if (tid < 12) {
        int c0 = c_CDAYS[tid], c1 = c_CDAYS[tid + 1];
        float s = 0.f;
        for (int i = c0; i < c1; ++i) s += dtsi[i];
        sGE[tid] = (s / (float)(c1 - c0)) / maxd;
        float nd = c_NDAYSF[tid + 1];
        float jm = (float)c0 + 0.5f * nd;
        float ms = 1.f - tl * tanf(23.439f * PI_F / 180.f * cosf(jm * PI_F / 182.625f));
        ms = fminf(2.f, fmaxf(0.f, ms));
        float nhrs = 24.f * acosf(1.f - ms) / PI_F;
        sL[tid] = nd / 30.f * (nhrs / 12.f);
    }
    __syncthreads();

    // ---- PET -> A per staged year-group ----
    for (int g = tid; g < NGRP; g += BS) {
        int yg = blockIdx.x * BY - WARM_Y + g;
        int pt = g * 13;
        if (yg < 0 || yg >= nyrs) {
#pragma unroll
            for (int m = 0; m < 12; ++m) sA[pt + m] = 1.f;   // identity step (B==0)
            continue;
        }
        float I = 0.f;
#pragma unroll
        for (int m = 0; m < 12; ++m) {
            float is = fmaxf(sT[pt + m] * 0.2f, 0.f);
            I += fpow(is, 1.514f);
        }
        float a  = 6.75e-07f * I * I * I - 7.71e-05f * I * I + 0.0179f * I + 0.49f;
        float rI = 10.0f / I;
#pragma unroll
        for (int m = 0; m < 12; ++m) {
            float t = sT[pt + m];
            float ep;
            if (t < 0.f)          ep = 0.f;
            else if (t < 26.5f)   ep = 16.f * sL[m] * fpow(t * rI, a);
            else                  ep = -415.85f + 32.25f * t - 0.43f * t * t;
            sA[pt + m] = (1.0f - 0.093f) - ep * (1.0f / 760.0f);
        }
    }
    __syncthreads();

    // ---- per-thread soil-moisture chain: 12 warm years + 1 real year ----
    const int ly = tid;
    const int y = blockIdx.x * BY + ly;
    if (y >= nyrs) return;
    const float invT = 1.0f / (T2 - T1);
    const float invM = 1.0f / (M2 - M1);

    float M = 0.2f;
    int g0 = (blockIdx.x == 0) ? (ly < WARM_Y ? WARM_Y : ly) : ly;

    for (int g = g0; g < ly + WARM_Y; ++g) {
        int pt = g * 13;
#pragma unroll
        for (int m = 0; m < 12; ++m) {
            float a = sA[pt + m], b = sB[pt + m];
            float pw = fexp2(fmaf(4.886f, flog2(M), POW_C));   // (M/0.76)^4.886
            float K = fmaf(a, M, b);
            M = fmaf(-b, pw, K);
            M = fminf(0.76f, fmaxf(0.01f, M));
        }
    }
    {
        int pt = (ly + WARM_Y) * 13;
        float acc = 0.f;
#pragma unroll
        for (int m = 0; m < 12; ++m) {
            float a = sA[pt + m], b = sB[pt + m];
            float pw = fexp2(fmaf(4.886f, flog2(M), POW_C));
            float K = fmaf(a, M, b);
            M = fmaf(-b, pw, K);
            M = fminf(0.76f, fmaxf(0.01f, M));
            float gT = fminf(fmaxf((sT[pt + m] - T1) * invT, 0.f), 1.f);
            float gM = fminf(fmaxf((M - M1) * invM, 0.f), 1.f);
            acc += fminf(gT, gM) * sGE[m];
        }
        width[y] = acc;
    }
}

// ---------------- z-score normalize in place (single block) ----------------
__global__ void k_norm(float* __restrict__ out, int n) {
    __shared__ double s_sum[256];
    __shared__ double s_sq[256];
    __shared__ float mean_s, inv_s;
    const int t = threadIdx.x;
    double sm = 0.0, sq = 0.0;
    for (int i = t; i < n; i += 256) {
        double w = (double)out[i];
        sm += w; sq += w * w;
    }
    s_sum[t] = sm; s_sq[t] = sq;
    __syncthreads();
    for (int off = 128; off > 0; off >>= 1) {
        if (t < off) { s_sum[t] += s_sum[t + off]; s_sq[t] += s_sq[t + off]; }
        __syncthreads();
    }
    if (t == 0) {
        double mean = s_sum[0] / (double)n;
        double var = (s_sq[0] - (double)n * mean * mean) / (double)(n - 1);
        mean_s = (float)mean;
        inv_s = (float)(1.0 / sqrt(var));
    }
    __syncthreads();
    for (int i = t; i < n; i += 256) {
        out[i] = (out[i] - mean_s) * inv_s;
    }
}

extern "C" void kernel_launch(void* const* d_in, const int* in_sizes, int n_in,
                              void* d_out, int out_size, void* d_ws, size_t ws_size,
                              hipStream_t stream) {
    // inputs: 0=syear 1=eyear 2=phi(int) 3=T(f32) 4=P(f32) 5=T1 6=T2 7=M1 8=M2
    const int*   phi = (const int*)d_in[2];
    const float* T   = (const float*)d_in[3];
    const float* P   = (const float*)d_in[4];
    const float* T1  = (const float*)d_in[5];
    const float* T2  = (const float*)d_in[6];
    const float* M1  = (const float*)d_in[7];
    const float* M2  = (const float*)d_in[8];
    float* out = (float*)d_out;

    const int nyrs = in_sizes[3] / 12;   // 8192

    k_fused<<<(nyrs + BY - 1) / BY, BS, 0, stream>>>(phi, T, P, T1, T2, M1, M2, out, nyrs);
    k_norm<<<1, 256, 0, stream>>>(out, nyrs);
}

// Round 4
// 90.531 us; speedup vs baseline: 1.7231x; 1.0845x over previous
//
#include <hip/hip_runtime.h>
#include <math.h>

#define PI_F 3.14159265358979323846f
#define WARM_Y 12          // warm-up years: 0.907^144 * 0.56 ~ 4e-7 residual in M
#define BY 64              // years per block (one wave of chains)
#define BS 256             // threads per block (4 waves; waves 1-3 help setup only)
#define NGRP (BY + WARM_Y) // 76 year-groups staged per block
#define NPAD (NGRP * 13)   // padded LDS floats (stride 13 -> conflict-free)

// Hardware log2/exp2 (v_log_f32/v_exp_f32). Args >= 0 here; 0 -> -inf -> 0 = pow(0,y).
#if __has_builtin(__builtin_amdgcn_logf) && __has_builtin(__builtin_amdgcn_exp2f)
__device__ __forceinline__ float flog2(float x) { return __builtin_amdgcn_logf(x); }
__device__ __forceinline__ float fexp2(float x) { return __builtin_amdgcn_exp2f(x); }
#else
__device__ __forceinline__ float flog2(float x) { return log2f(x); }
__device__ __forceinline__ float fexp2(float x) { return exp2f(x); }
#endif
__device__ __forceinline__ float fpow(float x, float y) { return fexp2(y * flog2(x)); }

__constant__ int   c_CDAYS[13]  = {0,31,59,90,120,151,181,212,243,273,304,334,365};
__constant__ float c_NDAYSF[13] = {0,31,28,31,30,31,30,31,31,30,31,30,31};

#define POW_C 1.9345076f   // 4.886 * log2(1/0.76): folds frac=M/0.76 into the exponent

// One fused kernel: insolation + PET + contractive soil scan + last-block z-score.
// ws layout: [0..3] counter (memset to 0 each launch), [16..] 2 doubles per block.
__global__ void k_all(const int* __restrict__ phi_ptr,
                      const float* __restrict__ T, const float* __restrict__ P,
                      const float* __restrict__ T1p, const float* __restrict__ T2p,
                      const float* __restrict__ M1p, const float* __restrict__ M2p,
                      float* out, unsigned int* ctr, double* partials, int nyrs) {
    __shared__ float sA[NPAD];
    __shared__ float sB[NPAD];
    __shared__ float sT[NPAD];
    __shared__ float dtsi[365];
    __shared__ float red[BS];
    __shared__ float sL[12], sGE[12];
    __shared__ int   is_last_s;
    __shared__ float mean_s, inv_s;

    const int tid = threadIdx.x;
    const float latr = (float)(*phi_ptr) * (PI_F / 180.f);
    const float tl = tanf(latr), slat = sinf(latr), clat = cosf(latr);
    const float T1 = *T1p, T2 = *T2p, M1 = *M1p, M2 = *M2p;

    // ---- insolation daily curve (identical per block; 2 rounds at BS=256) ----
    for (int d = tid; d < 365; d += BS) {
        float jd = (float)(d + 1);
        float sd = asinf(sinf(PI_F * 23.5f / 180.f) * sinf(PI_F * (jd - 80.f) / 180.f));
        float y  = fminf(1.f, fmaxf(-1.f, -tl * tanf(sd)));
        float hdl = acosf(y);
        dtsi[d] = hdl * slat * sinf(sd) + clat * cosf(sd) * sinf(hdl);
    }

    // ---- stage T, P (B = P/1000); out-of-range groups become identity steps ----
    const int nmon = nyrs * 12;
    const int base = (blockIdx.x * BY - WARM_Y) * 12;
    for (int t = tid; t < NGRP * 12; t += BS) {
        int tg = base + t;
        int pt = t + t / 12;                 // g*13 + m
        float p = 0.f, tt = 0.f;
        if (tg >= 0 && tg < nmon) { p = P[tg]; tt = T[tg]; }
        sB[pt] = p * 1e-3f;
        sT[pt] = tt;
    }
    __syncthreads();

    // ---- max(dtsi) block reduction ----
    {
        float mx = -1e30f;
        for (int i = tid; i < 365; i += BS) mx = fmaxf(mx, dtsi[i]);
        red[tid] = mx;
        __syncthreads();
        for (int off = BS / 2; off > 0; off >>= 1) {
            if (tid < off) red[tid] = fmaxf(red[tid], red[tid + off]);
            __syncthreads();
        }
    }
    const float maxd = red[0];
    __syncthreads();

    // ---- monthly L, gE ----
    if (tid < 12) {
        int c0 = c_CDAYS[tid], c1 = c_CDAYS[tid + 1];
        float s = 0.f;
        for (int i = c0; i < c1; ++i) s += dtsi[i];
        sGE[tid] = (s / (float)(c1 - c0)) / maxd;
        float nd = c_NDAYSF[tid + 1];
        float jm = (float)c0 + 0.5f * nd;
        float ms = 1.f - tl * tanf(23.439f * PI_F / 180.f * cosf(jm * PI_F / 182.625f));
        ms = fminf(2.f, fmaxf(0.f, ms));
        float nhrs = 24.f * acosf(1.f - ms) / PI_F;
        sL[tid] = nd / 30.f * (nhrs / 12.f);
    }
    __syncthreads();

    // ---- PET -> linear coefficient A per staged year-group (1 round) ----
    if (tid < NGRP) {
        int g = tid;
        int yg = blockIdx.x * BY - WARM_Y + g;
        int pt = g * 13;
        if (yg < 0 || yg >= nyrs) {
#pragma unroll
            for (int m = 0; m < 12; ++m) sA[pt + m] = 1.f;   // identity (B==0)
        } else {
            float I = 0.f;
#pragma unroll
            for (int m = 0; m < 12; ++m) {
                float is = fmaxf(sT[pt + m] * 0.2f, 0.f);
                I += fpow(is, 1.514f);
            }
            float a  = 6.75e-07f * I * I * I - 7.71e-05f * I * I + 0.0179f * I + 0.49f;
            float rI = 10.0f / I;
#pragma unroll
            for (int m = 0; m < 12; ++m) {
                float t = sT[pt + m];
                float ep;
                if (t < 0.f)          ep = 0.f;
                else if (t < 26.5f)   ep = 16.f * sL[m] * fpow(t * rI, a);
                else                  ep = -415.85f + 32.25f * t - 0.43f * t * t;
                sA[pt + m] = (1.0f - 0.093f) - ep * (1.0f / 760.0f);
            }
        }
    }
    __syncthreads();

    // ---- wave 0: per-thread chain (12 warm-up years + 1 real year) ----
    double wsum = 0.0, wsq = 0.0;
    if (tid < BY) {
        const int ly = tid;
        const int y = blockIdx.x * BY + ly;
        const float invT = 1.0f / (T2 - T1);
        const float invM = 1.0f / (M2 - M1);
        float M = 0.2f;
        for (int g = ly; g < ly + WARM_Y; ++g) {     // identity groups make M0 exact
            int pt = g * 13;
#pragma unroll
            for (int m = 0; m < 12; ++m) {
                float a = sA[pt + m], b = sB[pt + m];
                float pw = fexp2(fmaf(4.886f, flog2(M), POW_C));   // (M/0.76)^4.886
                float K = fmaf(a, M, b);
                M = fmaf(-b, pw, K);
                M = fminf(0.76f, fmaxf(0.01f, M));
            }
        }
        float acc = 0.f;
        {
            int pt = (ly + WARM_Y) * 13;
#pragma unroll
            for (int m = 0; m < 12; ++m) {
                float a = sA[pt + m], b = sB[pt + m];
                float pw = fexp2(fmaf(4.886f, flog2(M), POW_C));
                float K = fmaf(a, M, b);
                M = fmaf(-b, pw, K);
                M = fminf(0.76f, fmaxf(0.01f, M));
                float gT = fminf(fmaxf((sT[pt + m] - T1) * invT, 0.f), 1.f);
                float gM = fminf(fmaxf((M - M1) * invM, 0.f), 1.f);
                acc += fminf(gT, gM) * sGE[m];
            }
        }
        if (y < nyrs) {
            out[y] = acc;
            wsum = (double)acc;
            wsq  = (double)acc * (double)acc;
        }
        // wave-level reduction of (sum, sumsq) across 64 lanes
        for (int off = 32; off > 0; off >>= 1) {
            wsum += __shfl_down(wsum, off);
            wsq  += __shfl_down(wsq,  off);
        }
        if (ly == 0) {
            partials[2 * blockIdx.x]     = wsum;
            partials[2 * blockIdx.x + 1] = wsq;
        }
    }
    __syncthreads();

    // ---- last-block-done: z-score normalize in place ----
    if (tid == 0) {
        __threadfence();                                  // release width+partials
        unsigned int old = atomicAdd(ctr, 1u);            // device-scope by default
        is_last_s = (old == gridDim.x - 1) ? 1 : 0;
    }
    __syncthreads();
    if (!is_last_s) return;
    __threadfence();                                      // acquire others' writes

    if (tid < 64) {
        const int nb = gridDim.x;
        double sm = 0.0, sq = 0.0;
        for (int b = tid; b < nb; b += 64) {
            sm += partials[2 * b];
            sq += partials[2 * b + 1];
        }
        for (int off = 32; off > 0; off >>= 1) {
            sm += __shfl_down(sm, off);
            sq += __shfl_down(sq, off);
        }
        if (tid == 0) {
            double mean = sm / (double)nyrs;
            double var  = (sq - (double)nyrs * mean * mean) / (double)(nyrs - 1);
            mean_s = (float)mean;
            inv_s  = (float)(1.0 / sqrt(var));
        }
    }
    __syncthreads();
    for (int i = tid; i < nyrs; i += BS) {
        out[i] = (out[i] - mean_s) * inv_s;
    }
}

extern "C" void kernel_launch(void* const* d_in, const int* in_sizes, int n_in,
                              void* d_out, int out_size, void* d_ws, size_t ws_size,
                              hipStream_t stream) {
    // inputs: 0=syear 1=eyear 2=phi(int) 3=T(f32) 4=P(f32) 5=T1 6=T2 7=M1 8=M2
    const int*   phi = (const int*)d_in[2];
    const float* T   = (const float*)d_in[3];
    const float* P   = (const float*)d_in[4];
    const float* T1  = (const float*)d_in[5];
    const float* T2  = (const float*)d_in[6];
    const float* M1  = (const float*)d_in[7];
    const float* M2  = (const float*)d_in[8];
    float* out = (float*)d_out;

    const int nyrs = in_sizes[3] / 12;   // 8192
    const int nblk = (nyrs + BY - 1) / BY;

    unsigned int* ctr = (unsigned int*)d_ws;                     // 4 B, zeroed below
    double* partials  = (double*)((char*)d_ws + 16);             // 2 doubles / block

    hipMemsetAsync(ctr, 0, sizeof(unsigned int), stream);        // capturable node
    k_all<<<nblk, BS, 0, stream>>>(phi, T, P, T1, T2, M1, M2, out, ctr, partials, nyrs);
}